// Round 5
// baseline (319.046 us; speedup 1.0000x reference)
//
#include <hip/hip_runtime.h>
#include <stdint.h>

// ---------- types ----------
typedef __attribute__((ext_vector_type(8))) __bf16 bf16x8;
typedef __attribute__((ext_vector_type(4))) float   f32x4;

__device__ __forceinline__ float bf2f(unsigned short u) {
    union { unsigned int i; float f; } v; v.i = ((unsigned int)u) << 16; return v.f;
}
__device__ __forceinline__ unsigned short f2bf(float f) {  // round-to-nearest-even
    unsigned int x = __builtin_bit_cast(unsigned int, f);
    x += 0x7FFFu + ((x >> 16) & 1u);
    return (unsigned short)(x >> 16);
}

// ---------- fp32 -> bf16 cast (vectorized, grid-stride) ----------
__global__ __launch_bounds__(256) void cast_kernel(const float* __restrict__ src,
                                                   unsigned short* __restrict__ dst, int n4) {
    int i = blockIdx.x * blockDim.x + threadIdx.x;
    int stride = gridDim.x * blockDim.x;
    const float4* s4 = (const float4*)src;
    ushort4* d4 = (ushort4*)dst;
    for (; i < n4; i += stride) {
        float4 v = s4[i];
        ushort4 o;
        o.x = f2bf(v.x); o.y = f2bf(v.y); o.z = f2bf(v.z); o.w = f2bf(v.w);
        d4[i] = o;
    }
}

// ---------- GEMM: C[M,NTOT] = A[M,K] * W[NTOT,K]^T  (bf16 in, fp32 accum) ----------
// 256x256 tile, BK=64, 512 threads = 8 waves (2M x 4N), per-wave output 128x64.
// m201-faithful 4-phase/K-tile schedule: per phase {reads; 1 half-tile stage;
// barrier; lgkmcnt(0); sched_barrier; setprio(1); 16 MFMA; setprio(0); barrier},
// counted vmcnt(4) gate folded into ph3's end barrier. 2-buffer LDS (128 KB),
// chunk-XOR swizzle (0 conflicts), XCD-aware mapping.
// MODE 0: += bias (split at col 256), store bf16 via LDS-coalesced epilogue.
// MODE 1: relu, store fp32 direct.
template<int NTOT, int MODE, int NTI>
__global__ __launch_bounds__(512, 2)
void gemm_bt(const unsigned short* __restrict__ A,
             const unsigned short* __restrict__ W,
             const float* __restrict__ bias0,
             const float* __restrict__ bias1,
             unsigned short* __restrict__ outb,
             float* __restrict__ outf) {
    constexpr int K  = 1024;
    constexpr int NT = 16;                 // K-tiles of 64
    __shared__ unsigned short lds[65536];  // 2 x (A 256x64 + B 256x64) = 128 KB

    const int t    = threadIdx.x;
    const int wave = t >> 6;
    const int lane = t & 63;

    const int bid = blockIdx.x;
    const int xcd = bid & 7;               // HW round-robins blocks over 8 XCDs
    const int j   = bid >> 3;
    const int mt  = xcd * 24 + j / NTI;    // 192 M-tiles, 24 per XCD
    const int nt  = j % NTI;

    const int wr = wave >> 2;              // 0..1 : M half (rows wr*128..)
    const int wc = wave & 3;               // 0..3 : N quarter (cols wc*64..)

    const size_t aBase = (size_t)mt * 256 * K;
    const size_t bBase = (size_t)nt * 256 * K;

    // staging: one gload_lds instr covers 64 rows x 128B; swizzled source col
    const int srow = t >> 3;                          // 0..63
    const int scol = ((t & 7) ^ (srow & 7)) << 3;     // element offset
    const unsigned short* gA = A + aBase + (size_t)srow * K + scol;
    const unsigned short* gB = W + bBase + (size_t)srow * K + scol;

    // stage one 128-row half (A or B) of tile `tile`: 2 x global_load_lds
    auto STAGE = [&](int tile, int isB, int half) {
        unsigned short* lb = lds + (tile & 1) * 32768 + isB * 16384 + half * 8192;
        const unsigned short* gp = (isB ? gB : gA) + (size_t)(half * 128) * K + tile * 64;
#pragma unroll
        for (int g = 0; g < 2; ++g)
            __builtin_amdgcn_global_load_lds(
                (const __attribute__((address_space(1))) void*)(gp + (size_t)(g * 64) * K),
                (__attribute__((address_space(3))) void*)(lb + g * 4096 + wave * 512), 16, 0, 0);
    };

    const int lr  = lane & 15;
    const int lkc = lane >> 4;
    auto LDA = [&](int buf, int mi, int kk) -> bf16x8 {
        const int row = wr * 128 + mi * 16 + lr;
        const int ch  = (kk * 4 + lkc) ^ (row & 7);
        return *reinterpret_cast<const bf16x8*>(&lds[buf * 32768 + row * 64 + ch * 8]);
    };
    auto LDB = [&](int buf, int ni, int kk) -> bf16x8 {
        const int row = wc * 64 + ni * 16 + lr;
        const int ch  = (kk * 4 + lkc) ^ (row & 7);
        return *reinterpret_cast<const bf16x8*>(&lds[buf * 32768 + 16384 + row * 64 + ch * 8]);
    };

    f32x4 acc[8][4];
#pragma unroll
    for (int m = 0; m < 8; ++m)
#pragma unroll
        for (int n = 0; n < 4; ++n) acc[m][n] = f32x4{0.f, 0.f, 0.f, 0.f};

    // prologue: B(0), A(0), B(1)  (12 loads; issue order defines vmcnt accounting)
    STAGE(0, 1, 0); STAGE(0, 1, 1);
    STAGE(0, 0, 0); STAGE(0, 0, 1);
    STAGE(1, 1, 0); STAGE(1, 1, 1);
    asm volatile("s_waitcnt vmcnt(4)" ::: "memory");   // tile 0 landed; B(1) in flight
    __builtin_amdgcn_s_barrier();
    asm volatile("" ::: "memory");

    bf16x8 af[4][2], bfr[4][2];

#define MID_BARRIER()                                      \
    asm volatile("" ::: "memory");                         \
    __builtin_amdgcn_s_barrier();                          \
    asm volatile("s_waitcnt lgkmcnt(0)" ::: "memory");     \
    __builtin_amdgcn_sched_barrier(0);

#define END_BARRIER()                                      \
    asm volatile("" ::: "memory");                         \
    __builtin_amdgcn_s_barrier();                          \
    asm volatile("" ::: "memory");

    for (int tt = 0; tt < NT; ++tt) {
        const int buf = tt & 1;

        // ---- ph0: reads A m0-3 + B n0-1; stage A-h0(tt+1); MFMA Q0 ----
#pragma unroll
        for (int m = 0; m < 4; ++m) { af[m][0] = LDA(buf, m, 0); af[m][1] = LDA(buf, m, 1); }
#pragma unroll
        for (int n = 0; n < 2; ++n) { bfr[n][0] = LDB(buf, n, 0); bfr[n][1] = LDB(buf, n, 1); }
        if (tt + 1 < NT) STAGE(tt + 1, 0, 0);
        MID_BARRIER();
        __builtin_amdgcn_s_setprio(1);
#pragma unroll
        for (int m = 0; m < 4; ++m)
#pragma unroll
            for (int n = 0; n < 2; ++n)
#pragma unroll
                for (int kk = 0; kk < 2; ++kk)
                    acc[m][n] = __builtin_amdgcn_mfma_f32_16x16x32_bf16(af[m][kk], bfr[n][kk], acc[m][n], 0, 0, 0);
        __builtin_amdgcn_s_setprio(0);
        END_BARRIER();

        // ---- ph1: reads B n2-3; stage A-h1(tt+1); MFMA Q1 ----
#pragma unroll
        for (int n = 0; n < 2; ++n) { bfr[2 + n][0] = LDB(buf, 2 + n, 0); bfr[2 + n][1] = LDB(buf, 2 + n, 1); }
        if (tt + 1 < NT) STAGE(tt + 1, 0, 1);
        MID_BARRIER();
        __builtin_amdgcn_s_setprio(1);
#pragma unroll
        for (int m = 0; m < 4; ++m)
#pragma unroll
            for (int n = 0; n < 2; ++n)
#pragma unroll
                for (int kk = 0; kk < 2; ++kk)
                    acc[m][2 + n] = __builtin_amdgcn_mfma_f32_16x16x32_bf16(af[m][kk], bfr[2 + n][kk], acc[m][2 + n], 0, 0, 0);
        __builtin_amdgcn_s_setprio(0);
        END_BARRIER();

        // ---- ph2: reads A m4-7; stage B-h0(tt+2); MFMA Q2 ----
#pragma unroll
        for (int m = 0; m < 4; ++m) { af[m][0] = LDA(buf, 4 + m, 0); af[m][1] = LDA(buf, 4 + m, 1); }
        if (tt + 2 < NT) STAGE(tt + 2, 1, 0);
        MID_BARRIER();
        __builtin_amdgcn_s_setprio(1);
#pragma unroll
        for (int m = 0; m < 4; ++m)
#pragma unroll
            for (int n = 0; n < 2; ++n)
#pragma unroll
                for (int kk = 0; kk < 2; ++kk)
                    acc[4 + m][n] = __builtin_amdgcn_mfma_f32_16x16x32_bf16(af[m][kk], bfr[n][kk], acc[4 + m][n], 0, 0, 0);
        __builtin_amdgcn_s_setprio(0);
        END_BARRIER();

        // ---- ph3: no reads; stage B-h1(tt+2); MFMA Q3; vmcnt gate ----
        if (tt + 2 < NT) STAGE(tt + 2, 1, 1);
        asm volatile("" ::: "memory");
        __builtin_amdgcn_s_barrier();
        __builtin_amdgcn_sched_barrier(0);
        __builtin_amdgcn_s_setprio(1);
#pragma unroll
        for (int m = 0; m < 4; ++m)
#pragma unroll
            for (int n = 0; n < 2; ++n)
#pragma unroll
                for (int kk = 0; kk < 2; ++kk)
                    acc[4 + m][2 + n] = __builtin_amdgcn_mfma_f32_16x16x32_bf16(af[m][kk], bfr[2 + n][kk], acc[4 + m][2 + n], 0, 0, 0);
        __builtin_amdgcn_s_setprio(0);
        if (tt < NT - 2)       asm volatile("s_waitcnt vmcnt(4)" ::: "memory");  // tt+1 landed; B(tt+2) in flight
        else if (tt == NT - 2) asm volatile("s_waitcnt vmcnt(0)" ::: "memory");  // last tile landed
        END_BARRIER();
    }
#undef MID_BARRIER
#undef END_BARRIER

    // -------- epilogue --------
    const int rowOff = (lane >> 4) * 4;   // C/D: col = lane&15, row = rowOff + r
    if (MODE == 1) {
#pragma unroll
        for (int m = 0; m < 8; ++m)
#pragma unroll
            for (int n = 0; n < 4; ++n)
#pragma unroll
                for (int r = 0; r < 4; ++r)
                    outf[(size_t)(mt * 256 + wr * 128 + m * 16 + rowOff + r) * NTOT
                         + nt * 256 + wc * 64 + n * 16 + lr] = fmaxf(acc[m][n][r], 0.f);
    } else {
        unsigned short* lu = lds;         // 8 regions x 64 x 72 shorts
#pragma unroll
        for (int mh = 0; mh < 2; ++mh) {
            __syncthreads();
#pragma unroll
            for (int mq = 0; mq < 4; ++mq)
#pragma unroll
                for (int n = 0; n < 4; ++n) {
                    const int gc = nt * 256 + wc * 64 + n * 16 + lr;
                    const float bv = (gc < 256) ? bias0[gc] : bias1[gc - 256];
#pragma unroll
                    for (int r = 0; r < 4; ++r)
                        lu[wave * 4608 + (mq * 16 + rowOff + r) * 72 + n * 16 + lr] =
                            f2bf(acc[mh * 4 + mq][n][r] + bv);
                }
            __syncthreads();
#pragma unroll
            for (int it = 0; it < 8; ++it) {          // 128 rows x 256 cols bf16
                const int flat = it * 4096 + t * 8;   // shorts
                const int rp   = flat >> 8;           // 0..127
                const int col  = flat & 255;
                const int R    = (rp >> 6) * 128 + mh * 64 + (rp & 63);
                const int reg  = (rp >> 6) * 4 + (col >> 6);
                uint4 v = *reinterpret_cast<const uint4*>(&lu[reg * 4608 + (rp & 63) * 72 + (col & 63)]);
                *reinterpret_cast<uint4*>(outb + (size_t)(mt * 256 + R) * NTOT + nt * 256 + col) = v;
            }
        }
    }
}

// ---------- per-batch: sim -> mask -> softmax -> relation + agg (in-place over x_bf16) ----------
__global__ __launch_bounds__(256)
void relation_kernel(const unsigned short* __restrict__ TP,   // [M,512] bf16: theta|phi
                     const float* __restrict__ boxes,         // [M,4]
                     unsigned short* __restrict__ xagg,       // [M,1024] bf16 in, agg out (aliased)
                     float* __restrict__ relout) {            // [BT,12,12] fp32
    __shared__ float th[12][260];
    __shared__ float ph[12][260];
    __shared__ unsigned short xls[12 * 1024];
    __shared__ float cx[12], cy[12];
    __shared__ float sim[12][12];
    __shared__ float rel[12][12];

    const int b = blockIdx.x;
    const int t = threadIdx.x;

    if (t < 12) {
        const float* bx = boxes + ((size_t)b * 12 + t) * 4;
        cx[t] = (bx[0] + bx[2]) * 0.5f;
        cy[t] = (bx[1] + bx[3]) * 0.5f;
    }
    const uint4* tp4 = (const uint4*)(TP + (size_t)b * 6144);
    for (int c = t; c < 768; c += 256) {
        uint4 v = tp4[c];
        const unsigned short* pv = (const unsigned short*)&v;
        const int n = c >> 6;
        const int c0 = (c & 63) << 3;
        if (c0 < 256) {
#pragma unroll
            for (int jj = 0; jj < 8; ++jj) th[n][c0 + jj] = bf2f(pv[jj]);
        } else {
#pragma unroll
            for (int jj = 0; jj < 8; ++jj) ph[n][c0 - 256 + jj] = bf2f(pv[jj]);
        }
    }
    const uint4* x4 = (const uint4*)(xagg + (size_t)b * 12288);
    uint4* xl4 = (uint4*)xls;
    for (int c = t; c < 1536; c += 256) xl4[c] = x4[c];
    __syncthreads();

    if (t < 144) {
        const int n = t / 12, m = t - (t / 12) * 12;
        float a = 0.f;
#pragma unroll 8
        for (int r = 0; r < 256; ++r) a += th[n][r] * ph[m][r];
        const float dx = cx[n] - cx[m], dy = cy[n] - cy[m];
        const float d2 = dx * dx + dy * dy;
        const float thr = 31.4f;  // POS_THRESHOLD * OW
        sim[n][m] = (d2 > thr * thr) ? -__builtin_inff() : a * 0.0625f;
    }
    __syncthreads();

    if (t < 12) {
        float mx = -__builtin_inff();
#pragma unroll
        for (int m = 0; m < 12; ++m) mx = fmaxf(mx, sim[t][m]);
        float e[12]; float s = 0.f;
#pragma unroll
        for (int m = 0; m < 12; ++m) { e[m] = expf(sim[t][m] - mx); s += e[m]; }
        const float inv = 1.f / s;
#pragma unroll
        for (int m = 0; m < 12; ++m) {
            const float r = e[m] * inv;
            rel[t][m] = r;
            relout[(size_t)b * 144 + t * 12 + m] = r;
        }
    }
    __syncthreads();

    unsigned short* aggp = xagg + (size_t)b * 12288;
    for (int f = t; f < 1024; f += 256) {
        float xv[12];
#pragma unroll
        for (int m = 0; m < 12; ++m) xv[m] = bf2f(xls[m * 1024 + f]);
#pragma unroll
        for (int n = 0; n < 12; ++n) {
            float a = 0.f;
#pragma unroll
            for (int m = 0; m < 12; ++m) a += rel[n][m] * xv[m];
            aggp[n * 1024 + f] = f2bf(a);
        }
    }
}

// ---------- launcher ----------
extern "C" void kernel_launch(void* const* d_in, const int* in_sizes, int n_in,
                              void* d_out, int out_size, void* d_ws, size_t ws_size,
                              hipStream_t stream) {
    const float* x     = (const float*)d_in[0];  // [4096,12,1024]
    const float* boxes = (const float*)d_in[1];  // [49152,4]
    const float* Wth   = (const float*)d_in[2];  // [256,1024]
    const float* bth   = (const float*)d_in[3];  // [256]
    const float* Wph   = (const float*)d_in[4];  // [256,1024]
    const float* bph   = (const float*)d_in[5];  // [256]
    const float* Wg    = (const float*)d_in[6];  // [1024,1024]
    float* out = (float*)d_out;                  // 49152*1024 out | 4096*144 relation

    const int M = 49152;
    const size_t XE = (size_t)M * 1024;

    char* ws = (char*)d_ws;
    unsigned short* xb   = (unsigned short*)ws;                 // bf16 x, later agg (in place)
    unsigned short* TP   = (unsigned short*)(ws + 100663296);   // [M,512] bf16 theta|phi
    unsigned short* Wcat = (unsigned short*)(ws + 150994944);   // [512,1024] bf16
    unsigned short* Wgb  = (unsigned short*)(ws + 152043520);   // [1024,1024] bf16

    cast_kernel<<<2048, 256, 0, stream>>>(x, xb, (int)(XE / 4));
    cast_kernel<<<128, 256, 0, stream>>>(Wth, Wcat, 262144 / 4);
    cast_kernel<<<128, 256, 0, stream>>>(Wph, Wcat + 262144, 262144 / 4);
    cast_kernel<<<256, 256, 0, stream>>>(Wg, Wgb, 1048576 / 4);

    // 192 M-tiles (24/XCD); grid = 192 * NTI, NTI = NTOT/256
    gemm_bt<512, 0, 2><<<dim3(192 * 2), 512, 0, stream>>>(xb, Wcat, bth, bph, TP, nullptr);

    relation_kernel<<<4096, 256, 0, stream>>>(TP, boxes, xb, out + XE);

    gemm_bt<1024, 1, 4><<<dim3(192 * 4), 512, 0, stream>>>(xb, Wgb, nullptr, nullptr, nullptr, out);
}